// Round 16
// baseline (1539.579 us; speedup 1.0000x reference)
//
#include <hip/hip_runtime.h>
#include <hip/hip_fp16.h>

// Persistent fused GRU + value head, MI355X (gfx950).
// T=512,B=256,I=64,H=512.
// R29 = R28 (8 publishers/group, spill-proof 256-thr/4-wave blocks, green)
// with ONE fix: X(t+1) loads moved AFTER the flag publish. R28 put them
// before the ack, so vmcnt(0) waited on X's possible HBM miss (~900cy) in
// addition to the h-store drain — delaying every consumer's flag. Now the
// ack drains ONLY the h-store (the "memory" clobber on the ack asm stops
// the compiler hoisting the plain X loads above it), and X latency hides
// in the post-publish window (next poll's dead time) — exactly the role
// R26's service wave played.
// Geometry: 128 blocks x 256 thr (4 MFMA waves, 1 wave/SIMD -> full VGPR
// budget, R28 measured 188 VGPR, no spill). 16 groups x 8 blocks x 64
// units; per-wave work champion-bit-exact (16 units/wave, same fragments,
// slab layout u_base=64*jb+16*wv, same FP order, same MALL scopes).
// Tail: h-store -> value-head -> ack vmcnt(0) -> barrier joins 4 waves ->
// tid==0 publishes ONE flag (8/group) -> X(t+1) loads -> x-GEMM(t+1) ->
// part store.
// Straggler/serialization model: R26's clean A/B (32->16 flag publishers)
// = -570cy/step; 16->8 predicted -200-300cy more once unconfounded.
// HARD RULE (R15/R17): every VMEM-load ASM block contains its own s_waitcnt.

#define T_  512
#define B_  256
#define I_  64
#define H_  512
#define NBG 16
#define BT  16                  // batch rows per group
#define NMW 4                   // MFMA waves per block (all waves)
#define BLOCK 256               // 4 waves -> 1 wave/SIMD -> full VGPR budget
#define NSL 32                  // value-head slices (16 units each)

typedef _Float16 f16;
typedef _Float16 f16x8 __attribute__((ext_vector_type(8)));
typedef float    f32x4 __attribute__((ext_vector_type(4)));
typedef unsigned int u32x2 __attribute__((ext_vector_type(2)));

__device__ __forceinline__ float sigmoid_f(float x) { return 1.f / (1.f + __expf(-x)); }
__device__ __forceinline__ float tanh_f(float x) {
    float e2 = __expf(2.f * x);
    return 1.f - 2.f / (e2 + 1.f);
}

__global__ __launch_bounds__(BLOCK, 1) void gru_persistent(
    const float* __restrict__ X, const float* __restrict__ Wih,
    const float* __restrict__ Whh, const float* __restrict__ bih,
    const float* __restrict__ bhh, const float* __restrict__ vw,
    const float* __restrict__ bias, float* __restrict__ Vout,
    f16* __restrict__ hbuf, unsigned int* __restrict__ flags,
    float* __restrict__ part, const int use_part)
{
    const int blk  = blockIdx.x;                   // 128 blocks
    const int g    = (blk & 7) * 2 + (blk >> 6);   // 16 groups; members share blk%8
    const int jb   = (blk >> 3) & 7;               // block-within-group 0..7
    const int b0   = g * BT;
    const int tid  = threadIdx.x;
    const int wv   = tid >> 6;                     // 0..3 (all MFMA)
    const int lane = tid & 63;
    const int quad = lane >> 4;
    const int mrow = lane & 15;

    unsigned int* gflags = flags + (size_t)g * 32;  // one 128B line per group

    // ============ weights=A (units on M), h/x=B (batch on N) ============
    // wave owns units [64*jb + 16*wv, +16) — champion-bit-exact per wave.
    f16x8 wh[3][16];
    f16x8 wxA[3][2];
    const int um = 64 * jb + wv * 16 + mrow;
    #pragma unroll
    for (int g3 = 0; g3 < 3; g3++) {
        const size_t grow = (size_t)(g3 * H_ + um);
        #pragma unroll
        for (int kt = 0; kt < 16; kt++) {
            const float* src = Whh + grow * H_ + kt * 32 + quad * 8;
            #pragma unroll
            for (int e = 0; e < 8; e++) wh[g3][kt][e] = (f16)src[e];
        }
        #pragma unroll
        for (int kt = 0; kt < 2; kt++) {
            const float* src = Wih + grow * I_ + kt * 32 + quad * 8;
            #pragma unroll
            for (int e = 0; e < 8; e++) wxA[g3][kt][e] = (f16)src[e];
        }
    }
    float b_r4[4], b_z4[4], b_ni4[4], b_nh4[4], vw4[4];
    #pragma unroll
    for (int r = 0; r < 4; r++) {
        const int ub = 64 * jb + wv * 16 + quad * 4 + r;
        b_r4[r]  = bih[ub] + bhh[ub];
        b_z4[r]  = bih[H_ + ub] + bhh[H_ + ub];
        b_ni4[r] = bih[2 * H_ + ub];
        b_nh4[r] = bhh[2 * H_ + ub];
        vw4[r]   = vw[ub];
    }
    float hprev[4] = {0.f, 0.f, 0.f, 0.f};   // fp32 anchor for z*h (t=0 zeros)
    unsigned int* blkflag = gflags + jb;     // ONE flag per block (8/group)
    const int sl = 4 * jb + wv;              // value-head slice (16 units)
    const float bias0 = bias[0];
    const f32x4 zero = {0.f, 0.f, 0.f, 0.f};
    // h store offset: u = 64*jb + 16*wv + 4*quad + r ->
    // idx = (u>>3)*128 + mrow*8 + (u&7), (u>>3) = 8*jb + 2*wv + (quad>>1)
    const size_t hoff = (size_t)((8 * jb + 2 * wv + (quad >> 1)) * 128
                                 + mrow * 8 + (quad & 1) * 4);
    // per-lane X fragment base: row b0+mrow, cols quad*8.. and 32+quad*8..
    const float* xrow = X + (size_t)(b0 + mrow) * I_ + quad * 8;

    // ---- x-GEMM for t=0, loop-carried (plain loads; cast == service wave's) ----
    f32x4 xr, xz, xni;
    {
        float4 a0 = *(const float4*)(xrow);
        float4 a1 = *(const float4*)(xrow + 4);
        float4 c0 = *(const float4*)(xrow + 32);
        float4 c1 = *(const float4*)(xrow + 36);
        f16x8 bx0 = {(f16)a0.x,(f16)a0.y,(f16)a0.z,(f16)a0.w,
                     (f16)a1.x,(f16)a1.y,(f16)a1.z,(f16)a1.w};
        f16x8 bx1 = {(f16)c0.x,(f16)c0.y,(f16)c0.z,(f16)c0.w,
                     (f16)c1.x,(f16)c1.y,(f16)c1.z,(f16)c1.w};
        xr  = __builtin_amdgcn_mfma_f32_16x16x32_f16(wxA[0][0], bx0, zero, 0, 0, 0);
        xz  = __builtin_amdgcn_mfma_f32_16x16x32_f16(wxA[1][0], bx0, zero, 0, 0, 0);
        xni = __builtin_amdgcn_mfma_f32_16x16x32_f16(wxA[2][0], bx0, zero, 0, 0, 0);
        xr  = __builtin_amdgcn_mfma_f32_16x16x32_f16(wxA[0][1], bx1, xr,  0, 0, 0);
        xz  = __builtin_amdgcn_mfma_f32_16x16x32_f16(wxA[1][1], bx1, xz,  0, 0, 0);
        xni = __builtin_amdgcn_mfma_f32_16x16x32_f16(wxA[2][1], bx1, xni, 0, 0, 0);
    }

    #pragma unroll 1
    for (int t = 0; t < T_; t++) {
        // ---- 1. ballot poll: 8 block-flags in one line (lane<8) ----
        if (t > 0) {
            const unsigned target = (unsigned)t;
            for (;;) {
                unsigned v = target;
                if (lane < 8) {
                    const unsigned int* fp = gflags + lane;
                    asm volatile("global_load_dword %0, %1, off sc0 sc1\n\t"
                                 "s_waitcnt vmcnt(0)"
                                 : "=v"(v) : "v"(fp) : "memory");
                }
                if (__ballot(v >= target) == ~0ull) break;
            }
        }

        // ---- 2. h_{t-1} fragments: 16 x 1KB loads, vmcnt(0) INSIDE asm ----
        f16x8 afr[16];
        const char* pb = (const char*)(hbuf
                       + ((size_t)((t & 1) ^ 1) * NBG + g) * 8192)
                       + quad * 256 + mrow * 16;
        asm volatile(
            "global_load_dwordx4 %0, %16, off sc0 sc1\n\t"
            "global_load_dwordx4 %1, %16, off offset:1024 sc0 sc1\n\t"
            "global_load_dwordx4 %2, %16, off offset:2048 sc0 sc1\n\t"
            "global_load_dwordx4 %3, %16, off offset:3072 sc0 sc1\n\t"
            "global_load_dwordx4 %4, %17, off sc0 sc1\n\t"
            "global_load_dwordx4 %5, %17, off offset:1024 sc0 sc1\n\t"
            "global_load_dwordx4 %6, %17, off offset:2048 sc0 sc1\n\t"
            "global_load_dwordx4 %7, %17, off offset:3072 sc0 sc1\n\t"
            "global_load_dwordx4 %8, %18, off sc0 sc1\n\t"
            "global_load_dwordx4 %9, %18, off offset:1024 sc0 sc1\n\t"
            "global_load_dwordx4 %10, %18, off offset:2048 sc0 sc1\n\t"
            "global_load_dwordx4 %11, %18, off offset:3072 sc0 sc1\n\t"
            "global_load_dwordx4 %12, %19, off sc0 sc1\n\t"
            "global_load_dwordx4 %13, %19, off offset:1024 sc0 sc1\n\t"
            "global_load_dwordx4 %14, %19, off offset:2048 sc0 sc1\n\t"
            "global_load_dwordx4 %15, %19, off offset:3072 sc0 sc1\n\t"
            "s_waitcnt vmcnt(0)"
            : "=&v"(afr[0]), "=&v"(afr[1]), "=&v"(afr[2]), "=&v"(afr[3]),
              "=&v"(afr[4]), "=&v"(afr[5]), "=&v"(afr[6]), "=&v"(afr[7]),
              "=&v"(afr[8]), "=&v"(afr[9]), "=&v"(afr[10]), "=&v"(afr[11]),
              "=&v"(afr[12]), "=&v"(afr[13]), "=&v"(afr[14]), "=&v"(afr[15])
            : "v"(pb), "v"(pb + 4096), "v"(pb + 8192), "v"(pb + 12288)
            : "memory");

        // ---- 3. h-MFMA chain seeded by the loop-carried x-GEMM result ----
        f32x4 a_r = xr, a_z = xz, a_ni = xni;
        f32x4 a_nh = zero;
        #pragma unroll
        for (int kt = 0; kt < 16; kt++) {
            a_r  = __builtin_amdgcn_mfma_f32_16x16x32_f16(wh[0][kt], afr[kt], a_r,  0, 0, 0);
            a_z  = __builtin_amdgcn_mfma_f32_16x16x32_f16(wh[1][kt], afr[kt], a_z,  0, 0, 0);
            a_nh = __builtin_amdgcn_mfma_f32_16x16x32_f16(wh[2][kt], afr[kt], a_nh, 0, 0, 0);
        }

        // ---- 4. gates in registers; one 8B fragment-major h-store/lane ----
        float hn[4];
        union { f16 h[4]; u32x2 v; } pk;
        #pragma unroll
        for (int r = 0; r < 4; r++) {
            float rg = sigmoid_f(a_r[r] + b_r4[r]);
            float zg = sigmoid_f(a_z[r] + b_z4[r]);
            float ng = tanh_f(a_ni[r] + b_ni4[r] + rg * (a_nh[r] + b_nh4[r]));
            hn[r] = (1.f - zg) * ng + zg * hprev[r];
            hprev[r] = hn[r];
            pk.h[r] = (f16)hn[r];
        }
        {
            f16* hp = hbuf + ((size_t)(t & 1) * NBG + g) * 8192 + hoff;
            asm volatile("global_store_dwordx2 %0, %1, off sc0 sc1"
                         :: "v"(hp), "v"(pk.v) : "memory");
        }
        // value-head partial overlaps the store's flight time
        float s = hn[0] * vw4[0] + hn[1] * vw4[1] + hn[2] * vw4[2] + hn[3] * vw4[3];
        s += __shfl_xor(s, 16);
        s += __shfl_xor(s, 32);

        // ---- 5. ack drains ONLY the h-store -> barrier joins 4 waves ->
        //         ONE flag per block (8 publishers/group) ----
        asm volatile("s_waitcnt vmcnt(0)" ::: "memory");   // own h at MALL
        __syncthreads();                                    // 4 waves acked
        if (tid == 0)
            __hip_atomic_store(blkflag, (unsigned)(t + 1),
                               __ATOMIC_RELAXED, __HIP_MEMORY_SCOPE_AGENT);
        __builtin_amdgcn_sched_barrier(0);   // publish before X/x-GEMM work

        // ---- 6. X(t+1) loads + x-GEMM + part store in the post-publish
        //         window (overlaps the next poll's dead time; the "memory"
        //         clobber above keeps the loads below the ack) ----
        if (t + 1 < T_) {
            const float* xs = xrow + (size_t)(t + 1) * (B_ * I_);
            float4 a0 = *(const float4*)(xs);
            float4 a1 = *(const float4*)(xs + 4);
            float4 c0 = *(const float4*)(xs + 32);
            float4 c1 = *(const float4*)(xs + 36);
            f16x8 bx0 = {(f16)a0.x,(f16)a0.y,(f16)a0.z,(f16)a0.w,
                         (f16)a1.x,(f16)a1.y,(f16)a1.z,(f16)a1.w};
            f16x8 bx1 = {(f16)c0.x,(f16)c0.y,(f16)c0.z,(f16)c0.w,
                         (f16)c1.x,(f16)c1.y,(f16)c1.z,(f16)c1.w};
            xr  = __builtin_amdgcn_mfma_f32_16x16x32_f16(wxA[0][0], bx0, zero, 0, 0, 0);
            xz  = __builtin_amdgcn_mfma_f32_16x16x32_f16(wxA[1][0], bx0, zero, 0, 0, 0);
            xni = __builtin_amdgcn_mfma_f32_16x16x32_f16(wxA[2][0], bx0, zero, 0, 0, 0);
            xr  = __builtin_amdgcn_mfma_f32_16x16x32_f16(wxA[0][1], bx1, xr,  0, 0, 0);
            xz  = __builtin_amdgcn_mfma_f32_16x16x32_f16(wxA[1][1], bx1, xz,  0, 0, 0);
            xni = __builtin_amdgcn_mfma_f32_16x16x32_f16(wxA[2][1], bx1, xni, 0, 0, 0);
        }
        if (quad == 0) {
            if (use_part) part[(size_t)sl * (T_ * B_) + (size_t)t * B_ + b0 + mrow] = s;
            else atomicAdd(&Vout[(size_t)t * B_ + b0 + mrow], s + (sl == 0 ? bias0 : 0.f));
        }
    }
}

__global__ __launch_bounds__(256) void value_reduce(
    const float* __restrict__ part, const float* __restrict__ bias,
    float* __restrict__ Vout)
{
    const int i = blockIdx.x * 256 + threadIdx.x;   // i < T_*B_
    float s = bias[0];
    #pragma unroll
    for (int sl = 0; sl < NSL; sl++) s += part[(size_t)sl * (T_ * B_) + i];
    Vout[i] = s;
}

extern "C" void kernel_launch(void* const* d_in, const int* in_sizes, int n_in,
                              void* d_out, int out_size, void* d_ws, size_t ws_size,
                              hipStream_t stream) {
    const float* X    = (const float*)d_in[0];
    const float* Wih  = (const float*)d_in[1];
    const float* Whh  = (const float*)d_in[2];
    const float* bih  = (const float*)d_in[3];
    const float* bhh  = (const float*)d_in[4];
    const float* vw   = (const float*)d_in[5];
    const float* bias = (const float*)d_in[6];
    float* Vout = (float*)d_out;

    f16* hbuf = (f16*)d_ws;
    const size_t hbytes    = (size_t)2 * B_ * H_ * sizeof(f16);        // 512 KB
    const size_t flagbytes = (size_t)NBG * 32 * sizeof(unsigned);      // 2 KB (1 line/group)
    unsigned int* flags = (unsigned int*)((char*)d_ws + hbytes);
    float* part = (float*)((char*)d_ws + hbytes + flagbytes);
    const size_t partbytes = (size_t)NSL * T_ * B_ * sizeof(float);    // 16.8 MB
    const int use_part = (ws_size >= hbytes + flagbytes + partbytes) ? 1 : 0;

    hipMemsetAsync(d_ws, 0, hbytes + flagbytes, stream);   // hbuf zeros (t=0) + flags
    if (!use_part)
        hipMemsetAsync(d_out, 0, (size_t)out_size * sizeof(float), stream);

    gru_persistent<<<128, BLOCK, 0, stream>>>(X, Wih, Whh, bih, bhh, vw, bias,
                                              Vout, hbuf, flags, part, use_part);
    if (use_part)
        value_reduce<<<(T_ * B_) / 256, 256, 0, stream>>>(part, bias, Vout);
}

// Round 17
// 1319.273 us; speedup vs baseline: 1.1670x; 1.1670x over previous
//
#include <hip/hip_runtime.h>
#include <hip/hip_fp16.h>

// Persistent fused GRU + value head, MI355X (gfx950).
// T=512,B=256,I=64,H=512. 256 blocks = 16 batch groups x 16 hidden slices.
// R30 = R26 VERBATIM — final restore of the session champion (harness
// 1322us, dispatches 1250-1260; -10% vs session start 1407).
// R26's win: PER-BLOCK flag (16 publishers/group instead of 32), published
// after {per-wave vmcnt(0) ack -> existing __syncthreads joins both MFMA
// waves}. Confirmed the straggler-max-over-publishers model with a clean
// A/B (-570cy/step), zero register cost.
// Publisher lever exhausted at 16 — every 8-publisher route is blocked:
//   R27 (320thr, 8 pubs + service wave): compiler grants 128 VGPR -> spill;
//   R28/R29 (256thr, 8 pubs, X on MFMA waves): X staging on the critical
//   path costs more than publisher reduction saves (1433/1525 vs 1250).
// Other families closed earlier: sc0-only exchange falsified on HW
// (R15/R20), tagged self-validation register-infeasible (R21), two-group
// interleave -47% (R22), compute reorders neutral (R18/R19).
// Remaining structure: straggler-max over 16 MALL flag publishes + 1 MALL
// h-load RT + publish/ack + compute — a cross-XCD sync-latency floor, not
// a memory/compute roofline (HBM 2.5%, MfmaUtil 7.6%).
// HARD RULE (R15/R17): every VMEM-load asm block contains its own s_waitcnt.

#define T_  512
#define B_  256
#define I_  64
#define H_  512
#define NBG 16
#define BT  16                  // batch rows per group
#define HS  32                  // hidden units per block
#define BLOCK 192
#define NSL 32                  // value-head slices (j,wv)

typedef _Float16 f16;
typedef _Float16 f16x8 __attribute__((ext_vector_type(8)));
typedef float    f32x4 __attribute__((ext_vector_type(4)));
typedef unsigned int u32x2 __attribute__((ext_vector_type(2)));

__device__ __forceinline__ float sigmoid_f(float x) { return 1.f / (1.f + __expf(-x)); }
__device__ __forceinline__ float tanh_f(float x) {
    float e2 = __expf(2.f * x);
    return 1.f - 2.f / (e2 + 1.f);
}

__global__ __launch_bounds__(BLOCK, 1) void gru_persistent(
    const float* __restrict__ X, const float* __restrict__ Wih,
    const float* __restrict__ Whh, const float* __restrict__ bih,
    const float* __restrict__ bhh, const float* __restrict__ vw,
    const float* __restrict__ bias, float* __restrict__ Vout,
    f16* __restrict__ hbuf, unsigned int* __restrict__ flags,
    float* __restrict__ part, const int use_part)
{
    const int blk  = blockIdx.x;
    const int g    = (blk & 7) * 2 + (blk >> 7);   // group members share blk%8
    const int j    = (blk >> 3) & 15;
    const int b0   = g * BT;
    const int tid  = threadIdx.x;
    const int wv   = tid >> 6;
    const int lane = tid & 63;
    const int quad = lane >> 4;
    const int mrow = lane & 15;

    __shared__ __align__(16) f16 sh_x[2][BT][I_ + 8];   // X_t ping-pong (f16), padded
    unsigned int* gflags = flags + (size_t)g * 32;       // one 128B line per group

    if (wv < 2) {
        // ============ MFMA waves: weights=A (units on M), h/x=B (batch on N) ============
        // A[m=lane&15 -> unit][k=quad*8+e]; D: row=quad*4+r -> unit, col=lane&15 -> batch
        f16x8 wh[3][16];
        f16x8 wxA[3][2];
        const int um = HS * j + wv * 16 + mrow;
        #pragma unroll
        for (int g3 = 0; g3 < 3; g3++) {
            const size_t grow = (size_t)(g3 * H_ + um);
            #pragma unroll
            for (int kt = 0; kt < 16; kt++) {
                const float* src = Whh + grow * H_ + kt * 32 + quad * 8;
                #pragma unroll
                for (int e = 0; e < 8; e++) wh[g3][kt][e] = (f16)src[e];
            }
            #pragma unroll
            for (int kt = 0; kt < 2; kt++) {
                const float* src = Wih + grow * I_ + kt * 32 + quad * 8;
                #pragma unroll
                for (int e = 0; e < 8; e++) wxA[g3][kt][e] = (f16)src[e];
            }
        }
        float b_r4[4], b_z4[4], b_ni4[4], b_nh4[4], vw4[4];
        #pragma unroll
        for (int r = 0; r < 4; r++) {
            const int ub = HS * j + wv * 16 + quad * 4 + r;
            b_r4[r]  = bih[ub] + bhh[ub];
            b_z4[r]  = bih[H_ + ub] + bhh[H_ + ub];
            b_ni4[r] = bih[2 * H_ + ub];
            b_nh4[r] = bhh[2 * H_ + ub];
            vw4[r]   = vw[ub];
        }
        float hprev[4] = {0.f, 0.f, 0.f, 0.f};   // fp32 anchor for z*h (t=0 zeros)
        unsigned int* blkflag = gflags + j;      // ONE flag per block (16/group)
        const int sl = j * 2 + wv;
        const float bias0 = bias[0];
        const f32x4 zero = {0.f, 0.f, 0.f, 0.f};

        __syncthreads();   // init: service staged X_0 into slot 0

        // ---- x-GEMM for t=0 (slot 0), loop-carried into the first iteration ----
        f32x4 xr, xz, xni;
        {
            f16x8 bx0 = *(const f16x8*)&sh_x[0][mrow][quad * 8];
            f16x8 bx1 = *(const f16x8*)&sh_x[0][mrow][32 + quad * 8];
            xr  = __builtin_amdgcn_mfma_f32_16x16x32_f16(wxA[0][0], bx0, zero, 0, 0, 0);
            xz  = __builtin_amdgcn_mfma_f32_16x16x32_f16(wxA[1][0], bx0, zero, 0, 0, 0);
            xni = __builtin_amdgcn_mfma_f32_16x16x32_f16(wxA[2][0], bx0, zero, 0, 0, 0);
            xr  = __builtin_amdgcn_mfma_f32_16x16x32_f16(wxA[0][1], bx1, xr,  0, 0, 0);
            xz  = __builtin_amdgcn_mfma_f32_16x16x32_f16(wxA[1][1], bx1, xz,  0, 0, 0);
            xni = __builtin_amdgcn_mfma_f32_16x16x32_f16(wxA[2][1], bx1, xni, 0, 0, 0);
        }

        #pragma unroll 1
        for (int t = 0; t < T_; t++) {
            // ---- 1. ballot poll: 16 block-flags in one line (lane<16) ----
            if (t > 0) {
                const unsigned target = (unsigned)t;
                for (;;) {
                    unsigned v = target;
                    if (lane < 16) {
                        const unsigned int* fp = gflags + lane;
                        asm volatile("global_load_dword %0, %1, off sc0 sc1\n\t"
                                     "s_waitcnt vmcnt(0)"
                                     : "=v"(v) : "v"(fp) : "memory");
                    }
                    if (__ballot(v >= target) == ~0ull) break;
                }
            }

            // ---- 2. h_{t-1} fragments: fragment-major slab, 16 x 1KB-contiguous
            //         loads, vmcnt(0) INSIDE the asm (hard rule) ----
            f16x8 afr[16];
            const char* pb = (const char*)(hbuf
                           + ((size_t)((t & 1) ^ 1) * NBG + g) * 8192)
                           + quad * 256 + mrow * 16;
            asm volatile(
                "global_load_dwordx4 %0, %16, off sc0 sc1\n\t"
                "global_load_dwordx4 %1, %16, off offset:1024 sc0 sc1\n\t"
                "global_load_dwordx4 %2, %16, off offset:2048 sc0 sc1\n\t"
                "global_load_dwordx4 %3, %16, off offset:3072 sc0 sc1\n\t"
                "global_load_dwordx4 %4, %17, off sc0 sc1\n\t"
                "global_load_dwordx4 %5, %17, off offset:1024 sc0 sc1\n\t"
                "global_load_dwordx4 %6, %17, off offset:2048 sc0 sc1\n\t"
                "global_load_dwordx4 %7, %17, off offset:3072 sc0 sc1\n\t"
                "global_load_dwordx4 %8, %18, off sc0 sc1\n\t"
                "global_load_dwordx4 %9, %18, off offset:1024 sc0 sc1\n\t"
                "global_load_dwordx4 %10, %18, off offset:2048 sc0 sc1\n\t"
                "global_load_dwordx4 %11, %18, off offset:3072 sc0 sc1\n\t"
                "global_load_dwordx4 %12, %19, off sc0 sc1\n\t"
                "global_load_dwordx4 %13, %19, off offset:1024 sc0 sc1\n\t"
                "global_load_dwordx4 %14, %19, off offset:2048 sc0 sc1\n\t"
                "global_load_dwordx4 %15, %19, off offset:3072 sc0 sc1\n\t"
                "s_waitcnt vmcnt(0)"
                : "=&v"(afr[0]), "=&v"(afr[1]), "=&v"(afr[2]), "=&v"(afr[3]),
                  "=&v"(afr[4]), "=&v"(afr[5]), "=&v"(afr[6]), "=&v"(afr[7]),
                  "=&v"(afr[8]), "=&v"(afr[9]), "=&v"(afr[10]), "=&v"(afr[11]),
                  "=&v"(afr[12]), "=&v"(afr[13]), "=&v"(afr[14]), "=&v"(afr[15])
                : "v"(pb), "v"(pb + 4096), "v"(pb + 8192), "v"(pb + 12288)
                : "memory");

            // ---- 3. h-MFMA chain seeded by the loop-carried x-GEMM result ----
            f32x4 a_r = xr, a_z = xz, a_ni = xni;
            f32x4 a_nh = zero;
            #pragma unroll
            for (int kt = 0; kt < 16; kt++) {
                a_r  = __builtin_amdgcn_mfma_f32_16x16x32_f16(wh[0][kt], afr[kt], a_r,  0, 0, 0);
                a_z  = __builtin_amdgcn_mfma_f32_16x16x32_f16(wh[1][kt], afr[kt], a_z,  0, 0, 0);
                a_nh = __builtin_amdgcn_mfma_f32_16x16x32_f16(wh[2][kt], afr[kt], a_nh, 0, 0, 0);
            }

            // ---- 4. gates in registers; one 8B fragment-major h-store/lane ----
            float hn[4];
            union { f16 h[4]; u32x2 v; } pk;
            #pragma unroll
            for (int r = 0; r < 4; r++) {
                float rg = sigmoid_f(a_r[r] + b_r4[r]);
                float zg = sigmoid_f(a_z[r] + b_z4[r]);
                float ng = tanh_f(a_ni[r] + b_ni4[r] + rg * (a_nh[r] + b_nh4[r]));
                hn[r] = (1.f - zg) * ng + zg * hprev[r];
                hprev[r] = hn[r];
                pk.h[r] = (f16)hn[r];
            }
            {
                // h[batch=mrow][u=32j+16wv+4quad+r] -> idx=(u>>3)*128 + mrow*8 + (u&7)
                f16* hp = hbuf + ((size_t)(t & 1) * NBG + g) * 8192
                        + (size_t)((4 * j + 2 * wv + (quad >> 1)) * 128
                                   + mrow * 8 + (quad & 1) * 4);
                asm volatile("global_store_dwordx2 %0, %1, off sc0 sc1"
                             :: "v"(hp), "v"(pk.v) : "memory");
            }
            // value-head partial overlaps the store's flight time
            float s = hn[0] * vw4[0] + hn[1] * vw4[1] + hn[2] * vw4[2] + hn[3] * vw4[3];
            s += __shfl_xor(s, 16);
            s += __shfl_xor(s, 32);

            // ---- 5. per-wave ack -> barrier joins both waves' acks (and is the
            //         X ping-pong fence) -> ONE flag per block ----
            asm volatile("s_waitcnt vmcnt(0)" ::: "memory");   // own h at MALL
            __syncthreads();                                    // both waves acked
            if (tid == 0)
                __hip_atomic_store(blkflag, (unsigned)(t + 1),
                                   __ATOMIC_RELAXED, __HIP_MEMORY_SCOPE_AGENT);
            __builtin_amdgcn_sched_barrier(0);   // publish before x-GEMM work

            // ---- 6. x-GEMM(t+1) + part store fill the post-publish window ----
            if (t + 1 < T_) {
                f16x8 bx0 = *(const f16x8*)&sh_x[(t + 1) & 1][mrow][quad * 8];
                f16x8 bx1 = *(const f16x8*)&sh_x[(t + 1) & 1][mrow][32 + quad * 8];
                xr  = __builtin_amdgcn_mfma_f32_16x16x32_f16(wxA[0][0], bx0, zero, 0, 0, 0);
                xz  = __builtin_amdgcn_mfma_f32_16x16x32_f16(wxA[1][0], bx0, zero, 0, 0, 0);
                xni = __builtin_amdgcn_mfma_f32_16x16x32_f16(wxA[2][0], bx0, zero, 0, 0, 0);
                xr  = __builtin_amdgcn_mfma_f32_16x16x32_f16(wxA[0][1], bx1, xr,  0, 0, 0);
                xz  = __builtin_amdgcn_mfma_f32_16x16x32_f16(wxA[1][1], bx1, xz,  0, 0, 0);
                xni = __builtin_amdgcn_mfma_f32_16x16x32_f16(wxA[2][1], bx1, xni, 0, 0, 0);
            }
            if (quad == 0) {
                if (use_part) part[(size_t)sl * (T_ * B_) + (size_t)t * B_ + b0 + mrow] = s;
                else atomicAdd(&Vout[(size_t)t * B_ + b0 + mrow], s + (sl == 0 ? bias0 : 0.f));
            }
        }
    } else {
        // ============== service wave: X_{t+1} -> LDS ping-pong (off-path) ==============
        const int bb = lane >> 2, seg = (lane & 3) * 16;
        {   // stage X_0 -> slot 0
            const float* xs = X + (size_t)(b0 + bb) * I_ + seg;
            const float4 x0 = *(const float4*)(xs + 0),  x1 = *(const float4*)(xs + 4);
            const float4 x2 = *(const float4*)(xs + 8),  x3 = *(const float4*)(xs + 12);
            f16* dst = &sh_x[0][bb][seg];
            f16x8 p0 = {(f16)x0.x,(f16)x0.y,(f16)x0.z,(f16)x0.w,(f16)x1.x,(f16)x1.y,(f16)x1.z,(f16)x1.w};
            f16x8 p1 = {(f16)x2.x,(f16)x2.y,(f16)x2.z,(f16)x2.w,(f16)x3.x,(f16)x3.y,(f16)x3.z,(f16)x3.w};
            *(f16x8*)dst = p0; *(f16x8*)(dst + 8) = p1;
        }
        __syncthreads();   // init barrier
        #pragma unroll 1
        for (int t = 0; t < T_; t++) {
            if (t + 1 < T_) {
                const float* xs = X + (size_t)(t + 1) * (B_ * I_) + (size_t)(b0 + bb) * I_ + seg;
                const float4 x0 = *(const float4*)(xs + 0),  x1 = *(const float4*)(xs + 4);
                const float4 x2 = *(const float4*)(xs + 8),  x3 = *(const float4*)(xs + 12);
                f16* dst = &sh_x[(t + 1) & 1][bb][seg];
                f16x8 p0 = {(f16)x0.x,(f16)x0.y,(f16)x0.z,(f16)x0.w,(f16)x1.x,(f16)x1.y,(f16)x1.z,(f16)x1.w};
                f16x8 p1 = {(f16)x2.x,(f16)x2.y,(f16)x2.z,(f16)x2.w,(f16)x3.x,(f16)x3.y,(f16)x3.z,(f16)x3.w};
                *(f16x8*)dst = p0; *(f16x8*)(dst + 8) = p1;
            }
            __syncthreads();
        }
    }
}

__global__ __launch_bounds__(256) void value_reduce(
    const float* __restrict__ part, const float* __restrict__ bias,
    float* __restrict__ Vout)
{
    const int i = blockIdx.x * 256 + threadIdx.x;   // i < T_*B_
    float s = bias[0];
    #pragma unroll
    for (int sl = 0; sl < NSL; sl++) s += part[(size_t)sl * (T_ * B_) + i];
    Vout[i] = s;
}

extern "C" void kernel_launch(void* const* d_in, const int* in_sizes, int n_in,
                              void* d_out, int out_size, void* d_ws, size_t ws_size,
                              hipStream_t stream) {
    const float* X    = (const float*)d_in[0];
    const float* Wih  = (const float*)d_in[1];
    const float* Whh  = (const float*)d_in[2];
    const float* bih  = (const float*)d_in[3];
    const float* bhh  = (const float*)d_in[4];
    const float* vw   = (const float*)d_in[5];
    const float* bias = (const float*)d_in[6];
    float* Vout = (float*)d_out;

    f16* hbuf = (f16*)d_ws;
    const size_t hbytes    = (size_t)2 * B_ * H_ * sizeof(f16);        // 512 KB
    const size_t flagbytes = (size_t)NBG * 32 * sizeof(unsigned);      // 2 KB (1 line/group)
    unsigned int* flags = (unsigned int*)((char*)d_ws + hbytes);
    float* part = (float*)((char*)d_ws + hbytes + flagbytes);
    const size_t partbytes = (size_t)NSL * T_ * B_ * sizeof(float);    // 16.8 MB
    const int use_part = (ws_size >= hbytes + flagbytes + partbytes) ? 1 : 0;

    hipMemsetAsync(d_ws, 0, hbytes + flagbytes, stream);   // hbuf zeros (t=0) + flags
    if (!use_part)
        hipMemsetAsync(d_out, 0, (size_t)out_size * sizeof(float), stream);

    gru_persistent<<<256, BLOCK, 0, stream>>>(X, Wih, Whh, bih, bhh, vw, bias,
                                              Vout, hbuf, flags, part, use_part);
    if (use_part)
        value_reduce<<<(T_ * B_) / 256, 256, 0, stream>>>(part, bias, Vout);
}